// Round 5
// baseline (217.423 us; speedup 1.0000x reference)
//
#include <hip/hip_runtime.h>
#include <hip/hip_fp16.h>

// ChebyshevKAN: y[b,o] = sum_{i,j} U_j(tanh(x[b,i])) * C[i,o,j]
//   B=65536, I=512, O=32, degree 8 (j=0..8).
// Strategy: f16 MFMA GEMM [B x 4096] * [4096 x 32], A generated in registers.
//   - j=0 term (U_0 = 1) folded into bias[o] = sum_i C[i,o,0].
//   - K order: chunk ci (32 i's) x steps j=1..8; each K-32 step = one j.
//   - A-frag (16x16x32): A[m=lane&15][k=quad*8+e] -> lane owns 8 consecutive i
//     of its row; U recurrence advances j in fp32 registers.
//   - R5 structural change: NO LDS, NO BARRIERS. B_sw is 256 KB and fragment-
//     ordered -> L2-resident (4 MiB/XCD), chunk working set 16 KB -> L1-hot.
//     Each wave loads its B fragments directly global->VGPR (coalesced
//     dwordx4, per-lane addr = bsw + L*16B + static offsets). Waves are fully
//     independent; no per-chunk vmcnt drain / lockstep. R0-R4 showed every
//     pipelining patch INSIDE the barrier structure regressed (+13 us); this
//     removes the structure instead.

typedef _Float16 half8 __attribute__((ext_vector_type(8)));
typedef float float4v __attribute__((ext_vector_type(4)));

#define N_ROWS   65536
#define N_I      512
#define N_O      32
#define N_CHUNKS 16          // 512 / 32
#define STEPS    8           // j = 1..8
#define CHUNK_F16 8192       // 8 steps * 2 tiles * 64 lanes * 8 f16

// ---- pack kernel: coeffs [512][32][9] fp32 -> B_sw fragment-ordered f16 ----
// B_sw flat index: ((s_glob*2 + t)*64 + L)*8 + jj
//   s_glob = ci*8 + (j-1); k_local(ii) = (L>>4)*8 + jj; i = ci*32 + ii
//   n(o) = t*16 + (L&15)
__global__ void pack_b(const float* __restrict__ coeffs, _Float16* __restrict__ bsw) {
    int id = blockIdx.x * blockDim.x + threadIdx.x;
    if (id >= 128 * 2 * 64 * 8) return;
    int jj = id & 7;
    int L  = (id >> 3) & 63;
    int t  = (id >> 9) & 1;
    int s  = id >> 10;                 // 0..127
    int ci = s >> 3, sl = s & 7;
    int j  = sl + 1;                   // 1..8
    int ii = ((L >> 4) << 3) + jj;
    int i  = ci * 32 + ii;
    int o  = t * 16 + (L & 15);
    bsw[id] = (_Float16)coeffs[(i * 32 + o) * 9 + j];
}

// ---- bias kernel: bias[o] = sum_i coeffs[i][o][0] ----
__global__ void bias_k(const float* __restrict__ coeffs, float* __restrict__ bias) {
    int o = blockIdx.x;     // 32 blocks
    int t = threadIdx.x;    // 64 threads = 1 wave
    float s = 0.f;
    for (int i = t; i < N_I; i += 64) s += coeffs[(i * 32 + o) * 9 + 0];
    for (int off = 32; off; off >>= 1) s += __shfl_down(s, off, 64);
    if (t == 0) bias[o] = s;
}

__device__ __forceinline__ float fast_tanh(float v) {
    // tanh(v) = 1 - 2/(exp(2v)+1); graceful at +-inf. ~2ulp, far below f16 quant.
    float e = __expf(2.0f * v);
    return __builtin_fmaf(-2.0f, __builtin_amdgcn_rcpf(e + 1.0f), 1.0f);
}

// ---- main kernel ----
// block = 256 thr = 4 independent waves (no barriers, no LDS);
// wave owns 32 rows (2 M-tiles) x 32 cols (2 N-tiles); grid = 512 blocks.
__global__ __launch_bounds__(256, 2) void cheby_main(
        const float* __restrict__ x, const _Float16* __restrict__ bsw,
        const float* __restrict__ bias, float* __restrict__ y) {
    const int tid = threadIdx.x;
    const int wv  = tid >> 6;
    const int L   = tid & 63;
    const int q   = L >> 4;       // quad 0..3
    const int mr  = L & 15;       // row-in-tile / col-in-tile
    const int m0  = blockIdx.x * 128 + wv * 32;
    const int r0  = m0 + mr;      // M-tile 0 row
    const int r1  = r0 + 16;      // M-tile 1 row

    const float* xrow0 = x + (size_t)r0 * N_I;
    const float* xrow1 = x + (size_t)r1 * N_I;
    // this lane's B-fragment base: element L*8 (16 bytes per lane)
    const _Float16* bl = bsw + L * 8;

    float4v acc[2][2];
#pragma unroll
    for (int a = 0; a < 2; ++a)
#pragma unroll
        for (int b = 0; b < 2; ++b)
#pragma unroll
            for (int e = 0; e < 4; ++e) acc[a][b][e] = 0.f;

    for (int ci = 0; ci < N_CHUNKS; ++ci) {
        // lane's 8 i's for this chunk: i = ci*32 + q*8 + e
        const int i0 = ci * 32 + q * 8;
        const float4v xa = *(const float4v*)(xrow0 + i0);
        const float4v xb = *(const float4v*)(xrow0 + i0 + 4);
        const float4v xc = *(const float4v*)(xrow1 + i0);
        const float4v xd = *(const float4v*)(xrow1 + i0 + 4);

        const _Float16* bc = bl + (size_t)ci * CHUNK_F16;   // chunk's fragments

        float w0[8], w1[8], up0[8], uc0[8], up1[8], uc1[8];
#pragma unroll
        for (int e = 0; e < 4; ++e) {
            w0[e]     = 2.0f * fast_tanh(xa[e]);
            w0[e + 4] = 2.0f * fast_tanh(xb[e]);
            w1[e]     = 2.0f * fast_tanh(xc[e]);
            w1[e + 4] = 2.0f * fast_tanh(xd[e]);
        }
#pragma unroll
        for (int e = 0; e < 8; ++e) {    // U_0 = 1, U_1 = 2*xt
            up0[e] = 1.0f; uc0[e] = w0[e];
            up1[e] = 1.0f; uc1[e] = w1[e];
        }

#pragma unroll
        for (int s = 0; s < STEPS; ++s) {    // j = s+1
            half8 a0, a1;
#pragma unroll
            for (int e = 0; e < 8; ++e) {
                a0[e] = (_Float16)uc0[e];
                a1[e] = (_Float16)uc1[e];
            }
            // B fragments straight from global (L1/L2-hot, coalesced dwordx4):
            // step s tile t lives at element (s*2+t)*512 within the chunk.
            const half8 b0 = *(const half8*)(bc + (s * 2 + 0) * 512);
            const half8 b1 = *(const half8*)(bc + (s * 2 + 1) * 512);
            acc[0][0] = __builtin_amdgcn_mfma_f32_16x16x32_f16(a0, b0, acc[0][0], 0, 0, 0);
            acc[0][1] = __builtin_amdgcn_mfma_f32_16x16x32_f16(a0, b1, acc[0][1], 0, 0, 0);
            acc[1][0] = __builtin_amdgcn_mfma_f32_16x16x32_f16(a1, b0, acc[1][0], 0, 0, 0);
            acc[1][1] = __builtin_amdgcn_mfma_f32_16x16x32_f16(a1, b1, acc[1][1], 0, 0, 0);
            // advance recurrence: U_{n+1} = 2*xt*U_n - U_{n-1}
#pragma unroll
            for (int e = 0; e < 8; ++e) {
                float n0 = __builtin_fmaf(w0[e], uc0[e], -up0[e]);
                float n1 = __builtin_fmaf(w1[e], uc1[e], -up1[e]);
                up0[e] = uc0[e]; uc0[e] = n0;
                up1[e] = uc1[e]; uc1[e] = n1;
            }
        }
    }

    // epilogue: C/D layout row = q*4 + e, col = mr (verified 16x16 mapping)
    const float b_n0 = bias[mr];
    const float b_n1 = bias[16 + mr];
#pragma unroll
    for (int mt = 0; mt < 2; ++mt) {
#pragma unroll
        for (int e = 0; e < 4; ++e) {
            const int r = m0 + mt * 16 + q * 4 + e;
            y[(size_t)r * N_O + mr]      = acc[mt][0][e] + b_n0;
            y[(size_t)r * N_O + 16 + mr] = acc[mt][1][e] + b_n1;
        }
    }
}

extern "C" void kernel_launch(void* const* d_in, const int* in_sizes, int n_in,
                              void* d_out, int out_size, void* d_ws, size_t ws_size,
                              hipStream_t stream) {
    const float* x      = (const float*)d_in[0];
    const float* coeffs = (const float*)d_in[1];
    float* yout = (float*)d_out;

    _Float16* bsw = (_Float16*)d_ws;                               // 131072 f16 = 256KB
    float* bias   = (float*)((char*)d_ws + 131072 * sizeof(_Float16));

    pack_b<<<512, 256, 0, stream>>>(coeffs, bsw);
    bias_k<<<32, 64, 0, stream>>>(coeffs, bias);
    cheby_main<<<512, 256, 0, stream>>>(x, bsw, bias, yout);
}

// Round 6
// 214.319 us; speedup vs baseline: 1.0145x; 1.0145x over previous
//
#include <hip/hip_runtime.h>
#include <hip/hip_fp16.h>

// ChebyshevKAN: y[b,o] = sum_{i,j} U_j(tanh(x[b,i])) * C[i,o,j]
//   B=65536, I=512, O=32, degree 8 (j=0..8).
// Strategy: f16 MFMA GEMM [B x 4096] * [4096 x 32], A generated in registers.
//   - j=0 term (U_0 = 1) folded into bias[o] = sum_i C[i,o,0].
//   - K order: chunk ci (32 i's) x steps j=1..8; each K-32 step = one j.
//   - A-frag (16x16x32): A[m=lane&15][k=quad*8+e] -> lane owns 8 consecutive i
//     of its row; U recurrence advances j in fp32 registers. No LDS for A.
//   - B pre-swizzled to fragment order; 16KB/chunk double-buffered in LDS.
//     LDS keeps B on lgkmcnt, decoupled from the x vmcnt stream (R5 showed
//     global B loads serialize each MFMA step on the vmcnt FIFO: +17 us).
//   - R6: cheby_main is BIT-IDENTICAL to the verified R0 kernel (200.0 us).
//     Only change: bias fused into pack kernel -> 2 launches instead of 3.
//     (R1/R2/R4/R5 showed every perturbation of the main loop regresses.)

typedef _Float16 half8 __attribute__((ext_vector_type(8)));
typedef float float4v __attribute__((ext_vector_type(4)));

#define N_ROWS   65536
#define N_I      512
#define N_O      32
#define N_CHUNKS 16          // 512 / 32
#define STEPS    8           // j = 1..8
#define CHUNK_F16 8192       // 8 steps * 2 tiles * 64 lanes * 8 f16

// ---- pack + bias kernel ----
// blocks 0..511: coeffs [512][32][9] fp32 -> B_sw fragment-ordered f16
//   B_sw flat index: ((s_glob*2 + t)*64 + L)*8 + jj
//   s_glob = ci*8 + (j-1); k_local(ii) = (L>>4)*8 + jj; i = ci*32 + ii
//   n(o) = t*16 + (L&15)
// block 512: bias[o] = sum_i coeffs[i][o][0]
__global__ void pack_b_bias(const float* __restrict__ coeffs,
                            _Float16* __restrict__ bsw,
                            float* __restrict__ bias) {
    if (blockIdx.x < 512) {
        int id = blockIdx.x * 256 + threadIdx.x;
        int jj = id & 7;
        int L  = (id >> 3) & 63;
        int t  = (id >> 9) & 1;
        int s  = id >> 10;                 // 0..127
        int ci = s >> 3, sl = s & 7;
        int j  = sl + 1;                   // 1..8
        int ii = ((L >> 4) << 3) + jj;
        int i  = ci * 32 + ii;
        int o  = t * 16 + (L & 15);
        bsw[id] = (_Float16)coeffs[(i * 32 + o) * 9 + j];
        return;
    }
    // bias block: 256 threads; o = t>>3 (0..31), partial p = t&7 sums 64 values
    int t = threadIdx.x;
    int o = t >> 3;
    int p = t & 7;
    float s = 0.f;
#pragma unroll
    for (int k = 0; k < 64; ++k) s += coeffs[((p + k * 8) * 32 + o) * 9 + 0];
    // reduce across the 8-lane group (groups are 8-aligned within the wave)
    s += __shfl_xor(s, 4, 64);
    s += __shfl_xor(s, 2, 64);
    s += __shfl_xor(s, 1, 64);
    if (p == 0) bias[o] = s;
}

__device__ __forceinline__ float fast_tanh(float v) {
    // tanh(v) = 1 - 2/(exp(2v)+1); graceful at +-inf. ~2ulp, far below f16 quant.
    float e = __expf(2.0f * v);
    return __builtin_fmaf(-2.0f, __builtin_amdgcn_rcpf(e + 1.0f), 1.0f);
}

// ---- main kernel (verbatim R0 — verified 200.0 us configuration) ----
// block = 256 thr = 4 waves; wave owns 32 rows (2 M-tiles) x 32 cols (2 N-tiles)
// grid = 512 blocks (2 blocks/CU)
__global__ __launch_bounds__(256, 2) void cheby_main(
        const float* __restrict__ x, const _Float16* __restrict__ bsw,
        const float* __restrict__ bias, float* __restrict__ y) {
    __shared__ __align__(16) _Float16 bl[2][CHUNK_F16];   // 2 x 16KB B double-buffer

    const int tid = threadIdx.x;
    const int wv  = tid >> 6;
    const int L   = tid & 63;
    const int q   = L >> 4;       // quad 0..3
    const int mr  = L & 15;       // row-in-tile / col-in-tile
    const int m0  = blockIdx.x * 128 + wv * 32;
    const int r0  = m0 + mr;      // M-tile 0 row
    const int r1  = r0 + 16;      // M-tile 1 row

    // stage chunk 0 into buffer 0 (all 256 threads)
    {
        const uint4* src = (const uint4*)bsw;             // chunk0 at offset 0
        uint4* dst = (uint4*)&bl[0][0];
#pragma unroll
        for (int it = 0; it < 4; ++it) dst[it * 256 + tid] = src[it * 256 + tid];
    }

    float4v acc[2][2];
#pragma unroll
    for (int a = 0; a < 2; ++a)
#pragma unroll
        for (int b = 0; b < 2; ++b)
#pragma unroll
            for (int e = 0; e < 4; ++e) acc[a][b][e] = 0.f;

    for (int ci = 0; ci < N_CHUNKS; ++ci) {
        __syncthreads();                 // current buffer staged & prev reads done
        const int buf = ci & 1;
        if (ci < N_CHUNKS - 1) {         // prefetch next B chunk into other buffer
            const uint4* src = (const uint4*)(bsw + (ci + 1) * CHUNK_F16);
            uint4* dst = (uint4*)&bl[buf ^ 1][0];
#pragma unroll
            for (int it = 0; it < 4; ++it) dst[it * 256 + tid] = src[it * 256 + tid];
        }

        // lane's 8 i's for this chunk: i = ci*32 + q*8 + e
        const int i0 = ci * 32 + q * 8;
        const float4v xa = *(const float4v*)(x + (size_t)r0 * N_I + i0);
        const float4v xb = *(const float4v*)(x + (size_t)r0 * N_I + i0 + 4);
        const float4v xc = *(const float4v*)(x + (size_t)r1 * N_I + i0);
        const float4v xd = *(const float4v*)(x + (size_t)r1 * N_I + i0 + 4);

        float w0[8], w1[8], up0[8], uc0[8], up1[8], uc1[8];
#pragma unroll
        for (int e = 0; e < 4; ++e) {
            w0[e]     = 2.0f * fast_tanh(xa[e]);
            w0[e + 4] = 2.0f * fast_tanh(xb[e]);
            w1[e]     = 2.0f * fast_tanh(xc[e]);
            w1[e + 4] = 2.0f * fast_tanh(xd[e]);
        }
#pragma unroll
        for (int e = 0; e < 8; ++e) {    // U_0 = 1, U_1 = 2*xt
            up0[e] = 1.0f; uc0[e] = w0[e];
            up1[e] = 1.0f; uc1[e] = w1[e];
        }

#pragma unroll
        for (int s = 0; s < STEPS; ++s) {    // j = s+1
            half8 a0, a1;
#pragma unroll
            for (int e = 0; e < 8; ++e) {
                a0[e] = (_Float16)uc0[e];
                a1[e] = (_Float16)uc1[e];
            }
            const half8 b0 = *(const half8*)&bl[buf][(s * 2 + 0) * 512 + L * 8];
            const half8 b1 = *(const half8*)&bl[buf][(s * 2 + 1) * 512 + L * 8];
            acc[0][0] = __builtin_amdgcn_mfma_f32_16x16x32_f16(a0, b0, acc[0][0], 0, 0, 0);
            acc[0][1] = __builtin_amdgcn_mfma_f32_16x16x32_f16(a0, b1, acc[0][1], 0, 0, 0);
            acc[1][0] = __builtin_amdgcn_mfma_f32_16x16x32_f16(a1, b0, acc[1][0], 0, 0, 0);
            acc[1][1] = __builtin_amdgcn_mfma_f32_16x16x32_f16(a1, b1, acc[1][1], 0, 0, 0);
            // advance recurrence: U_{n+1} = 2*xt*U_n - U_{n-1}
#pragma unroll
            for (int e = 0; e < 8; ++e) {
                float n0 = __builtin_fmaf(w0[e], uc0[e], -up0[e]);
                float n1 = __builtin_fmaf(w1[e], uc1[e], -up1[e]);
                up0[e] = uc0[e]; uc0[e] = n0;
                up1[e] = uc1[e]; uc1[e] = n1;
            }
        }
    }

    // epilogue: C/D layout row = q*4 + e, col = mr (verified 16x16 mapping)
    const float b_n0 = bias[mr];
    const float b_n1 = bias[16 + mr];
#pragma unroll
    for (int mt = 0; mt < 2; ++mt) {
#pragma unroll
        for (int e = 0; e < 4; ++e) {
            const int r = m0 + mt * 16 + q * 4 + e;
            y[(size_t)r * N_O + mr]      = acc[mt][0][e] + b_n0;
            y[(size_t)r * N_O + 16 + mr] = acc[mt][1][e] + b_n1;
        }
    }
}

extern "C" void kernel_launch(void* const* d_in, const int* in_sizes, int n_in,
                              void* d_out, int out_size, void* d_ws, size_t ws_size,
                              hipStream_t stream) {
    const float* x      = (const float*)d_in[0];
    const float* coeffs = (const float*)d_in[1];
    float* yout = (float*)d_out;

    _Float16* bsw = (_Float16*)d_ws;                               // 131072 f16 = 256KB
    float* bias   = (float*)((char*)d_ws + 131072 * sizeof(_Float16));

    pack_b_bias<<<513, 256, 0, stream>>>(coeffs, bsw, bias);
    cheby_main<<<512, 256, 0, stream>>>(x, bsw, bias, yout);
}

// Round 7
// 196.670 us; speedup vs baseline: 1.1055x; 1.0897x over previous
//
#include <hip/hip_runtime.h>
#include <hip/hip_fp16.h>

// ChebyshevKAN: y[b,o] = sum_{i,j} U_j(tanh(x[b,i])) * C[i,o,j]
//   B=65536, I=512, O=32, degree 8 (j=0..8).
// Strategy: f16 MFMA GEMM [B x 4096] * [4096 x 32], A generated in registers.
//   - j=0 term (U_0 = 1) folded into bias[o] = sum_i C[i,o,0].
//   - K order: chunk ci (32 i's) x steps j=1..8; each K-32 step = one j.
//   - A-frag (16x16x32): A[m=lane&15][k=quad*8+e] -> lane owns 8 consecutive i
//     of its row; U recurrence advances j in fp32 registers. No LDS for A.
//   - B pre-swizzled to fragment order; 16KB/chunk double-buffered in LDS.
//     LDS keeps B on lgkmcnt, decoupled from the x vmcnt stream (R5: global B
//     loads serialize MFMA steps on the vmcnt FIFO, +17 us).
//   - cheby_main is BIT-IDENTICAL to the verified 200.0 us R0 kernel.
//   - R7: bias folded into the PACK GRID (blocks 0..31 each compute one bias
//     column with one wave, concurrent across 32 CUs). R6 proved the previous
//     fusion (bias as ONE extra block = 16K scattered loads on one CU) was a
//     +14 us straggler; R1/R4/R6's cluster at 213-214 attributes entirely to
//     it. This version has no straggler: fused kernel ~ max(pack, bias) and
//     one launch gap is removed.

typedef _Float16 half8 __attribute__((ext_vector_type(8)));
typedef float float4v __attribute__((ext_vector_type(4)));

#define N_ROWS   65536
#define N_I      512
#define N_O      32
#define N_CHUNKS 16          // 512 / 32
#define STEPS    8           // j = 1..8
#define CHUNK_F16 8192       // 8 steps * 2 tiles * 64 lanes * 8 f16

// ---- pack + distributed-bias kernel (512 blocks x 256 threads) ----
// All blocks: coeffs [512][32][9] fp32 -> B_sw fragment-ordered f16
//   B_sw flat index: ((s_glob*2 + t)*64 + L)*8 + jj
//   s_glob = ci*8 + (j-1); k_local(ii) = (L>>4)*8 + jj; i = ci*32 + ii
//   n(o) = t*16 + (L&15)
// Blocks 0..31: wave 0 additionally computes bias[o=blockIdx.x]
//   (8 scattered loads/thread — same per-block body as the old bias_k,
//    spread over 32 CUs, fully concurrent with pack work).
__global__ void pack_b_bias(const float* __restrict__ coeffs,
                            _Float16* __restrict__ bsw,
                            float* __restrict__ bias) {
    int id = blockIdx.x * 256 + threadIdx.x;
    {
        int jj = id & 7;
        int L  = (id >> 3) & 63;
        int t  = (id >> 9) & 1;
        int s  = id >> 10;                 // 0..127
        int ci = s >> 3, sl = s & 7;
        int j  = sl + 1;                   // 1..8
        int ii = ((L >> 4) << 3) + jj;
        int i  = ci * 32 + ii;
        int o  = t * 16 + (L & 15);
        bsw[id] = (_Float16)coeffs[(i * 32 + o) * 9 + j];
    }
    // distributed bias: block b < 32 handles column o = b with its wave 0
    if (blockIdx.x < 32 && threadIdx.x < 64) {
        int o = blockIdx.x;
        int t = threadIdx.x;
        float s = 0.f;
#pragma unroll
        for (int k = 0; k < 8; ++k) s += coeffs[((t + k * 64) * 32 + o) * 9 + 0];
        for (int off = 32; off; off >>= 1) s += __shfl_down(s, off, 64);
        if (t == 0) bias[o] = s;
    }
}

__device__ __forceinline__ float fast_tanh(float v) {
    // tanh(v) = 1 - 2/(exp(2v)+1); graceful at +-inf. ~2ulp, far below f16 quant.
    float e = __expf(2.0f * v);
    return __builtin_fmaf(-2.0f, __builtin_amdgcn_rcpf(e + 1.0f), 1.0f);
}

// ---- main kernel (verbatim R0 — verified 200.0 us configuration) ----
// block = 256 thr = 4 waves; wave owns 32 rows (2 M-tiles) x 32 cols (2 N-tiles)
// grid = 512 blocks (2 blocks/CU)
__global__ __launch_bounds__(256, 2) void cheby_main(
        const float* __restrict__ x, const _Float16* __restrict__ bsw,
        const float* __restrict__ bias, float* __restrict__ y) {
    __shared__ __align__(16) _Float16 bl[2][CHUNK_F16];   // 2 x 16KB B double-buffer

    const int tid = threadIdx.x;
    const int wv  = tid >> 6;
    const int L   = tid & 63;
    const int q   = L >> 4;       // quad 0..3
    const int mr  = L & 15;       // row-in-tile / col-in-tile
    const int m0  = blockIdx.x * 128 + wv * 32;
    const int r0  = m0 + mr;      // M-tile 0 row
    const int r1  = r0 + 16;      // M-tile 1 row

    // stage chunk 0 into buffer 0 (all 256 threads)
    {
        const uint4* src = (const uint4*)bsw;             // chunk0 at offset 0
        uint4* dst = (uint4*)&bl[0][0];
#pragma unroll
        for (int it = 0; it < 4; ++it) dst[it * 256 + tid] = src[it * 256 + tid];
    }

    float4v acc[2][2];
#pragma unroll
    for (int a = 0; a < 2; ++a)
#pragma unroll
        for (int b = 0; b < 2; ++b)
#pragma unroll
            for (int e = 0; e < 4; ++e) acc[a][b][e] = 0.f;

    for (int ci = 0; ci < N_CHUNKS; ++ci) {
        __syncthreads();                 // current buffer staged & prev reads done
        const int buf = ci & 1;
        if (ci < N_CHUNKS - 1) {         // prefetch next B chunk into other buffer
            const uint4* src = (const uint4*)(bsw + (ci + 1) * CHUNK_F16);
            uint4* dst = (uint4*)&bl[buf ^ 1][0];
#pragma unroll
            for (int it = 0; it < 4; ++it) dst[it * 256 + tid] = src[it * 256 + tid];
        }

        // lane's 8 i's for this chunk: i = ci*32 + q*8 + e
        const int i0 = ci * 32 + q * 8;
        const float4v xa = *(const float4v*)(x + (size_t)r0 * N_I + i0);
        const float4v xb = *(const float4v*)(x + (size_t)r0 * N_I + i0 + 4);
        const float4v xc = *(const float4v*)(x + (size_t)r1 * N_I + i0);
        const float4v xd = *(const float4v*)(x + (size_t)r1 * N_I + i0 + 4);

        float w0[8], w1[8], up0[8], uc0[8], up1[8], uc1[8];
#pragma unroll
        for (int e = 0; e < 4; ++e) {
            w0[e]     = 2.0f * fast_tanh(xa[e]);
            w0[e + 4] = 2.0f * fast_tanh(xb[e]);
            w1[e]     = 2.0f * fast_tanh(xc[e]);
            w1[e + 4] = 2.0f * fast_tanh(xd[e]);
        }
#pragma unroll
        for (int e = 0; e < 8; ++e) {    // U_0 = 1, U_1 = 2*xt
            up0[e] = 1.0f; uc0[e] = w0[e];
            up1[e] = 1.0f; uc1[e] = w1[e];
        }

#pragma unroll
        for (int s = 0; s < STEPS; ++s) {    // j = s+1
            half8 a0, a1;
#pragma unroll
            for (int e = 0; e < 8; ++e) {
                a0[e] = (_Float16)uc0[e];
                a1[e] = (_Float16)uc1[e];
            }
            const half8 b0 = *(const half8*)&bl[buf][(s * 2 + 0) * 512 + L * 8];
            const half8 b1 = *(const half8*)&bl[buf][(s * 2 + 1) * 512 + L * 8];
            acc[0][0] = __builtin_amdgcn_mfma_f32_16x16x32_f16(a0, b0, acc[0][0], 0, 0, 0);
            acc[0][1] = __builtin_amdgcn_mfma_f32_16x16x32_f16(a0, b1, acc[0][1], 0, 0, 0);
            acc[1][0] = __builtin_amdgcn_mfma_f32_16x16x32_f16(a1, b0, acc[1][0], 0, 0, 0);
            acc[1][1] = __builtin_amdgcn_mfma_f32_16x16x32_f16(a1, b1, acc[1][1], 0, 0, 0);
            // advance recurrence: U_{n+1} = 2*xt*U_n - U_{n-1}
#pragma unroll
            for (int e = 0; e < 8; ++e) {
                float n0 = __builtin_fmaf(w0[e], uc0[e], -up0[e]);
                float n1 = __builtin_fmaf(w1[e], uc1[e], -up1[e]);
                up0[e] = uc0[e]; uc0[e] = n0;
                up1[e] = uc1[e]; uc1[e] = n1;
            }
        }
    }

    // epilogue: C/D layout row = q*4 + e, col = mr (verified 16x16 mapping)
    const float b_n0 = bias[mr];
    const float b_n1 = bias[16 + mr];
#pragma unroll
    for (int mt = 0; mt < 2; ++mt) {
#pragma unroll
        for (int e = 0; e < 4; ++e) {
            const int r = m0 + mt * 16 + q * 4 + e;
            y[(size_t)r * N_O + mr]      = acc[mt][0][e] + b_n0;
            y[(size_t)r * N_O + 16 + mr] = acc[mt][1][e] + b_n1;
        }
    }
}

extern "C" void kernel_launch(void* const* d_in, const int* in_sizes, int n_in,
                              void* d_out, int out_size, void* d_ws, size_t ws_size,
                              hipStream_t stream) {
    const float* x      = (const float*)d_in[0];
    const float* coeffs = (const float*)d_in[1];
    float* yout = (float*)d_out;

    _Float16* bsw = (_Float16*)d_ws;                               // 131072 f16 = 256KB
    float* bias   = (float*)((char*)d_ws + 131072 * sizeof(_Float16));

    pack_b_bias<<<512, 256, 0, stream>>>(coeffs, bsw, bias);
    cheby_main<<<512, 256, 0, stream>>>(x, bsw, bias, yout);
}